// Round 2
// baseline (2482.951 us; speedup 1.0000x reference)
//
#include <hip/hip_runtime.h>

typedef _Float16 f16;
typedef __attribute__((ext_vector_type(8))) _Float16 f16x8;
typedef __attribute__((ext_vector_type(4))) _Float16 f16x4;
typedef __attribute__((ext_vector_type(4))) float floatx4;

#define BB 512
#define AA 100
#define HH 1024
#define KX 96          // padded x-part of K (77 -> 96)
#define KTOT 1120      // 1024 (h) + 96 (x)
#define NKC (KTOT / 32)
#define WSTR 1120      // Wcat row stride (f16 elems)
#define ASTR 1128      // LDS A row stride (f16 elems) - pad for bank spread

// ---------- prep kernels (one-time per launch, all cheap) ----------

// Wcat[n][0..1023] = (f16) W_hh[n][k]
__global__ __launch_bounds__(256) void cast_whh_k(const float* __restrict__ whh,
                                                  f16* __restrict__ wcat) {
  int gid = blockIdx.x * 256 + threadIdx.x;   // 1,048,576 threads
  int n = gid >> 8, k4 = (gid & 255) << 2;
  float4 v = *(const float4*)(whh + (size_t)n * HH + k4);
  f16x4 o; o[0] = (f16)v.x; o[1] = (f16)v.y; o[2] = (f16)v.z; o[3] = (f16)v.w;
  *(f16x4*)(wcat + (size_t)n * WSTR + k4) = o;
}

// Wcat[n][1024+j] = (W_ih @ W_emb)[n][j]  (j<77, zeros to 95)
// bcomb[n] = (W_ih @ b_emb)[n] + b_ih[n] + b_hh[n]
__global__ __launch_bounds__(512) void prep_wcomb_k(
    const float* __restrict__ wih, const float* __restrict__ wemb,
    const float* __restrict__ bemb, const float* __restrict__ bih,
    const float* __restrict__ bhh, f16* __restrict__ wcat,
    float* __restrict__ bcomb) {
  __shared__ float part[4][128];
  int n = blockIdx.x;                       // 4096 blocks
  int q = threadIdx.x >> 7, j = threadIdx.x & 127;
  float acc = 0.f;
  const float* wrow = wih + (size_t)n * HH + q * 256;
  if (j < 77) {
    const float* we = wemb + (size_t)(q * 256) * 77 + j;
    #pragma unroll 4
    for (int m = 0; m < 256; ++m) acc += wrow[m] * we[(size_t)m * 77];
  } else if (j == 96) {
    const float* be = bemb + q * 256;
    #pragma unroll 4
    for (int m = 0; m < 256; ++m) acc += wrow[m] * be[m];
  }
  part[q][j] = acc;
  __syncthreads();
  if (q == 0 && j < 97) {
    float s = part[0][j] + part[1][j] + part[2][j] + part[3][j];
    if (j < 96) {
      wcat[(size_t)n * WSTR + 1024 + j] = (f16)s;  // j in [77,96) -> 0
    } else {
      bcomb[n] = s + bih[n] + bhh[n];
    }
  }
}

// xh[(t*512+b)][i] = (f16) x[b, t, i]   (i<77; zero-pad to 96)
__global__ __launch_bounds__(256) void cast_x_k(const float* __restrict__ in,
                                                f16* __restrict__ xh) {
  int gid = blockIdx.x * 256 + threadIdx.x;  // 4,915,200 threads
  int row = gid / 96;
  int i = gid - row * 96;
  int t = row >> 9, b = row & 511;
  f16 v = (f16)0.f;
  if (i < 77) v = (f16)in[(size_t)b * 7700 + t * 77 + i];
  xh[(size_t)row * KX + i] = v;
}

__global__ __launch_bounds__(256) void init_hc_k(const float* __restrict__ h0,
                                                 const float* __restrict__ c0,
                                                 f16* __restrict__ h16,
                                                 float* __restrict__ cws) {
  int gid = blockIdx.x * 256 + threadIdx.x;  // 524,288 threads
  h16[gid] = (f16)h0[gid];
  cws[gid] = c0[gid];
}

// ---------- per-step fused GEMM + LSTM cell ----------

__device__ __forceinline__ float sigm(float x) { return 1.f / (1.f + __expf(-x)); }

// grid 512 blocks x 256 thr. Block tile: 32 batch rows x 32 h cols x 4 gates.
// Wave w computes gate w's 32x32 tile via 16x16x32 f16 MFMA, K=1120.
__global__ __launch_bounds__(256) void lstm_step_k(
    const f16* __restrict__ wcat, const float* __restrict__ bcomb,
    const f16* __restrict__ xh, const f16* __restrict__ hin,
    f16* __restrict__ hout, float* __restrict__ cws,
    float* __restrict__ outh, int t) {
  __shared__ __align__(16) char smem[32 * ASTR * 2];   // 72,192 B
  f16* alds = (f16*)smem;                              // A tile [32][ASTR]
  float (*glds)[32][34] = (float (*)[32][34])smem;     // reused post-barrier

  int tid = threadIdx.x;
  int id = blockIdx.x;                 // 512 blocks
  // XCD swizzle: keep all m-blocks of a given h-range on one XCD so the
  // W rows they share stay L2-resident (perf heuristic only).
  int xcd = id & 7, slot = id >> 3;    // slot 0..63
  int hb = xcd * 4 + (slot >> 4);      // 0..31
  int mb = slot & 15;                  // 0..15
  int m0 = mb * 32, h0 = hb * 32;

  // stage A = concat(h[32 rows][1024], x_t[32 rows][96]) into LDS
  for (int v = tid; v < 32 * 140; v += 256) {
    int row = v / 140, c8 = v - row * 140;
    int bg = m0 + row;
    const f16* src = (c8 < 128)
        ? (hin + (size_t)bg * HH + c8 * 8)
        : (xh + ((size_t)(t * BB + bg)) * KX + (c8 - 128) * 8);
    *(f16x8*)(alds + row * ASTR + c8 * 8) = *(const f16x8*)src;
  }
  __syncthreads();

  int w = tid >> 6, lane = tid & 63;
  int lr = lane & 15, lk = lane >> 4;

  int aoff0 = lr * ASTR + lk * 8;
  int aoff1 = (16 + lr) * ASTR + lk * 8;

  const f16* bp0 = wcat + (size_t)(w * HH + h0 + lr) * WSTR + lk * 8;
  const f16* bp1 = wcat + (size_t)(w * HH + h0 + 16 + lr) * WSTR + lk * 8;

  floatx4 acc00 = {0.f, 0.f, 0.f, 0.f};
  floatx4 acc01 = acc00, acc10 = acc00, acc11 = acc00;

  #pragma unroll 5
  for (int kc = 0; kc < NKC; ++kc) {
    f16x8 a0 = *(const f16x8*)(alds + aoff0 + kc * 32);
    f16x8 a1 = *(const f16x8*)(alds + aoff1 + kc * 32);
    f16x8 b0 = *(const f16x8*)(bp0 + kc * 32);
    f16x8 b1 = *(const f16x8*)(bp1 + kc * 32);
    acc00 = __builtin_amdgcn_mfma_f32_16x16x32_f16(a0, b0, acc00, 0, 0, 0);
    acc10 = __builtin_amdgcn_mfma_f32_16x16x32_f16(a1, b0, acc10, 0, 0, 0);
    acc01 = __builtin_amdgcn_mfma_f32_16x16x32_f16(a0, b1, acc01, 0, 0, 0);
    acc11 = __builtin_amdgcn_mfma_f32_16x16x32_f16(a1, b1, acc11, 0, 0, 0);
  }

  __syncthreads();  // all waves done reading alds; reuse LDS for gate exchange
  #pragma unroll
  for (int r = 0; r < 4; ++r) {
    // C/D layout: col = lane&15, row = (lane>>4)*4 + r  (verified m89/m91)
    glds[w][lk * 4 + r][lr]           = acc00[r];
    glds[w][lk * 4 + r][16 + lr]      = acc01[r];
    glds[w][16 + lk * 4 + r][lr]      = acc10[r];
    glds[w][16 + lk * 4 + r][16 + lr] = acc11[r];
  }
  __syncthreads();

  // LSTM cell: gates i,f,g,o (PyTorch order)
  #pragma unroll
  for (int e = tid; e < 32 * 32; e += 256) {
    int row = e >> 5, col = e & 31;
    int bg = m0 + row, hc = h0 + col;
    float gi = glds[0][row][col] + bcomb[hc];
    float gf = glds[1][row][col] + bcomb[HH + hc];
    float gg = glds[2][row][col] + bcomb[2 * HH + hc];
    float go = glds[3][row][col] + bcomb[3 * HH + hc];
    float iv = sigm(gi), fv = sigm(gf), gv = tanhf(gg), ov = sigm(go);
    size_t idx = (size_t)bg * HH + hc;
    float cn = fv * cws[idx] + iv * gv;
    float hn = ov * tanhf(cn);
    cws[idx] = cn;
    outh[idx] = hn;
    hout[idx] = (f16)hn;
  }
}

// ---------- launch ----------

extern "C" void kernel_launch(void* const* d_in, const int* in_sizes, int n_in,
                              void* d_out, int out_size, void* d_ws, size_t ws_size,
                              hipStream_t stream) {
  const float* inputs = (const float*)d_in[0];
  const float* h0     = (const float*)d_in[1];
  const float* c0     = (const float*)d_in[2];
  const float* W_emb  = (const float*)d_in[3];
  const float* b_emb  = (const float*)d_in[4];
  const float* W_ih   = (const float*)d_in[5];
  const float* W_hh   = (const float*)d_in[6];
  const float* b_ih   = (const float*)d_in[7];
  const float* b_hh   = (const float*)d_in[8];
  float* out = (float*)d_out;

  char* ws = (char*)d_ws;
  f16*   Wcat  = (f16*)(ws);                 // 4096*1120*2   = 9,175,040
  f16*   xh    = (f16*)(ws + 9175040);       // 51200*96*2    = 9,830,400
  f16*   h16a  = (f16*)(ws + 19005440);      // 512*1024*2    = 1,048,576
  f16*   h16b  = (f16*)(ws + 20054016);      // 512*1024*2    = 1,048,576
  float* c_ws  = (float*)(ws + 21102592);    // 512*1024*4    = 2,097,152
  float* bcomb = (float*)(ws + 23199744);    // 4096*4        = 16,384

  cast_whh_k  <<<4096, 256, 0, stream>>>(W_hh, Wcat);
  prep_wcomb_k<<<4096, 512, 0, stream>>>(W_ih, W_emb, b_emb, b_ih, b_hh, Wcat, bcomb);
  cast_x_k    <<<19200, 256, 0, stream>>>(inputs, xh);
  init_hc_k   <<<2048, 256, 0, stream>>>(h0, c0, h16a, c_ws);

  for (int t = 0; t < 100; ++t) {
    const f16* hin = (t & 1) ? h16b : h16a;
    f16* hout      = (t & 1) ? h16a : h16b;
    lstm_step_k<<<512, 256, 0, stream>>>(Wcat, bcomb, xh, hin, hout, c_ws,
                                         out + (size_t)t * BB * HH, t);
  }

  // h_f = h_99 (already fp32 in out[99]); c_f from workspace
  hipMemcpyAsync(out + (size_t)AA * BB * HH,
                 out + (size_t)99 * BB * HH,
                 (size_t)BB * HH * sizeof(float), hipMemcpyDeviceToDevice, stream);
  hipMemcpyAsync(out + (size_t)AA * BB * HH + (size_t)BB * HH,
                 c_ws,
                 (size_t)BB * HH * sizeof(float), hipMemcpyDeviceToDevice, stream);
}